// Round 1
// baseline (229.761 us; speedup 1.0000x reference)
//
#include <hip/hip_runtime.h>

// Problem constants (fixed by the reference)
#define BATCH 256
#define CDIM  2048
#define HW    49
#define KDIM  16
#define CHUNK 512      // C-range per block in kernel A
#define TILE  128      // C per LDS tile in kernel A
#define ROWP  52       // padded fm row (49 -> 52) so [cc][4*h4] float4 reads are 16B-aligned
#define WROWP 132      // padded w row (128 -> 132), 132*4 % 16 == 0, bank offset k*4

// ---------------------------------------------------------------------------
// Kernel A: partial P[k][hw] = sum over a 512-wide C chunk of fm[c][hw]*w[k][c]
// grid = BATCH*4, block = 256. Thread t owns k = t>>4 and hw quad 4*(t&15).
// ---------------------------------------------------------------------------
__global__ __launch_bounds__(256) void pconv_kernel(
    const float* __restrict__ fm, const float* __restrict__ w16,
    float* __restrict__ Ppart)
{
    __shared__ float fm_t[TILE * ROWP + 16];   // +16 pad: h4 up to 15 reads past row 127
    __shared__ float w_t[KDIM * WROWP];

    const int tid = threadIdx.x;
    const int b   = blockIdx.x >> 2;
    const int q   = blockIdx.x & 3;
    const int c0  = q * CHUNK;
    const int h4  = tid & 15;      // hw base = 4*h4 (hw 49..63 are discarded at write)
    const int k   = tid >> 4;      // 0..15

    float acc0 = 0.f, acc1 = 0.f, acc2 = 0.f, acc3 = 0.f;

    const float* fmb = fm + (size_t)b * CDIM * HW;

    for (int tile = 0; tile < CHUNK / TILE; ++tile) {
        const int ct = c0 + tile * TILE;
        __syncthreads();
        // --- load fm tile: TILE*HW = 6272 contiguous floats = 1568 float4 (16B aligned) ---
        const float4* src = (const float4*)(fmb + ct * HW);
        for (int i = tid; i < (TILE * HW) / 4; i += 256) {
            float4 v = src[i];
            int e = i * 4;
            int cl = e / HW; int h = e - cl * HW; fm_t[cl * ROWP + h] = v.x;
            e++; cl = e / HW; h = e - cl * HW;    fm_t[cl * ROWP + h] = v.y;
            e++; cl = e / HW; h = e - cl * HW;    fm_t[cl * ROWP + h] = v.z;
            e++; cl = e / HW; h = e - cl * HW;    fm_t[cl * ROWP + h] = v.w;
        }
        // --- load w tile: KDIM x TILE ---
        for (int i = tid; i < KDIM * TILE; i += 256) {
            int kk = i >> 7; int cc = i & 127;
            w_t[kk * WROWP + cc] = w16[kk * CDIM + ct + cc];
        }
        __syncthreads();
        // --- compute: reduce over cc; per 4 cc: 4x fm b128 + 1x w b128 + 16 FMA ---
        #pragma unroll 4
        for (int cc = 0; cc < TILE; cc += 4) {
            float4 wv = *(const float4*)&w_t[k * WROWP + cc];
            float4 f0 = *(const float4*)&fm_t[(cc + 0) * ROWP + 4 * h4];
            float4 f1 = *(const float4*)&fm_t[(cc + 1) * ROWP + 4 * h4];
            float4 f2 = *(const float4*)&fm_t[(cc + 2) * ROWP + 4 * h4];
            float4 f3 = *(const float4*)&fm_t[(cc + 3) * ROWP + 4 * h4];
            acc0 += f0.x * wv.x + f1.x * wv.y + f2.x * wv.z + f3.x * wv.w;
            acc1 += f0.y * wv.x + f1.y * wv.y + f2.y * wv.z + f3.y * wv.w;
            acc2 += f0.z * wv.x + f1.z * wv.y + f2.z * wv.z + f3.z * wv.w;
            acc3 += f0.w * wv.x + f1.w * wv.y + f2.w * wv.z + f3.w * wv.w;
        }
    }

    // write partial P: Ppart[blockIdx][k*49 + hw]
    float* dst = Ppart + (size_t)blockIdx.x * 784 + k * HW;
    const int hwb = 4 * h4;
    if (hwb + 0 < HW) dst[hwb + 0] = acc0;
    if (hwb + 1 < HW) dst[hwb + 1] = acc1;
    if (hwb + 2 < HW) dst[hwb + 2] = acc2;
    if (hwb + 3 < HW) dst[hwb + 3] = acc3;
}

// ---------------------------------------------------------------------------
// Kernel B: reduce 4 partials, apply BN + 1/49, then
// out[b][k][c] = sum_hw P_bn[k][hw] * fm[b][c][hw]
// grid = BATCH*8, block = 256. Thread t owns c = (blockIdx&7)*256 + t.
// ---------------------------------------------------------------------------
__global__ __launch_bounds__(256) void bp_kernel(
    const float* __restrict__ fm, const float* __restrict__ Ppart,
    const float* __restrict__ gamma, const float* __restrict__ beta,
    const float* __restrict__ mean, const float* __restrict__ var,
    float* __restrict__ out)
{
    __shared__ float Pt[HW * KDIM];   // [hw][k], 16B-aligned rows

    const int tid = threadIdx.x;
    const int b   = blockIdx.x >> 3;
    const int c0  = (blockIdx.x & 7) * 256;

    // phase 0: reduce partials + BN + fold 1/49, store transposed [hw][k]
    for (int p = tid; p < 784; p += 256) {
        const float* pp = Ppart + (size_t)(b * 4) * 784 + p;
        float s = pp[0] + pp[784] + pp[2 * 784] + pp[3 * 784];
        int kk = p / HW; int hw = p - kk * HW;
        float inv   = gamma[kk] * rsqrtf(var[kk] + 1e-5f);
        float shift = beta[kk] - mean[kk] * inv;
        Pt[hw * KDIM + kk] = (s * inv + shift) * (1.0f / 49.0f);
    }
    __syncthreads();

    const int c = c0 + tid;
    const float* row = fm + ((size_t)b * CDIM + c) * HW;

    float acc[16];
    #pragma unroll
    for (int i = 0; i < 16; ++i) acc[i] = 0.f;

    #pragma unroll 7
    for (int hw = 0; hw < HW; ++hw) {
        float f = row[hw];
        const float4* pv = (const float4*)&Pt[hw * KDIM];
        float4 p0 = pv[0], p1 = pv[1], p2 = pv[2], p3 = pv[3];
        acc[0]  += p0.x * f; acc[1]  += p0.y * f; acc[2]  += p0.z * f; acc[3]  += p0.w * f;
        acc[4]  += p1.x * f; acc[5]  += p1.y * f; acc[6]  += p1.z * f; acc[7]  += p1.w * f;
        acc[8]  += p2.x * f; acc[9]  += p2.y * f; acc[10] += p2.z * f; acc[11] += p2.w * f;
        acc[12] += p3.x * f; acc[13] += p3.y * f; acc[14] += p3.z * f; acc[15] += p3.w * f;
    }

    float* ob = out + (size_t)b * (KDIM * CDIM) + c;
    #pragma unroll
    for (int kk = 0; kk < 16; ++kk) ob[kk * CDIM] = acc[kk];
}

extern "C" void kernel_launch(void* const* d_in, const int* in_sizes, int n_in,
                              void* d_out, int out_size, void* d_ws, size_t ws_size,
                              hipStream_t stream) {
    const float* fm    = (const float*)d_in[0];
    const float* w16   = (const float*)d_in[1];
    const float* gamma = (const float*)d_in[2];
    const float* beta  = (const float*)d_in[3];
    const float* mean  = (const float*)d_in[4];
    const float* var   = (const float*)d_in[5];
    float* out   = (float*)d_out;
    float* Ppart = (float*)d_ws;   // needs BATCH*4*784*4 = 3.2 MB

    pconv_kernel<<<BATCH * 4, 256, 0, stream>>>(fm, w16, Ppart);
    bp_kernel<<<BATCH * 8, 256, 0, stream>>>(fm, Ppart, gamma, beta, mean, var, out);
}

// Round 2
// 215.237 us; speedup vs baseline: 1.0675x; 1.0675x over previous
//
#include <hip/hip_runtime.h>

// Problem constants (fixed by the reference)
#define BATCH 256
#define CDIM  2048
#define HW    49
#define KDIM  16
#define CHUNK 512      // C-range per block in kernel A
#define TILE  128      // C per LDS tile in kernel A
#define ROWP  52       // padded fm row: 52*4B=208B, 16B-aligned rows

// ---------------------------------------------------------------------------
// Kernel A: partial P[k][hw] = sum over a 512-wide C chunk of fm[c][hw]*w[k][c]
// grid = BATCH*4, block = 256.
// Thread t: h4 = t&15 (hw quad 4*h4), cs = t>>4 (c-slice of 8 cc per tile).
// Each thread accumulates ALL 16 k -> 5 ds_read_b128 per 64 MACs.
// ---------------------------------------------------------------------------
__global__ __launch_bounds__(256) void pconv_kernel(
    const float* __restrict__ fm, const float* __restrict__ w16,
    float* __restrict__ Ppart)
{
    __shared__ __align__(16) float fm_t[TILE * ROWP + 16];  // 6672 floats (~26.7KB)
    __shared__ __align__(16) float w_t[TILE * KDIM];        // [cc][k], 8KB

    const int tid = threadIdx.x;
    const int b   = blockIdx.x >> 2;
    const int q   = blockIdx.x & 3;
    const int c0  = q * CHUNK;
    const int h4  = tid & 15;     // hw quad; hw 49..63 lanes produce garbage, discarded
    const int cs  = tid >> 4;     // 0..15, c-slice within tile

    float acc[KDIM][4];
    #pragma unroll
    for (int k = 0; k < KDIM; ++k) {
        acc[k][0] = 0.f; acc[k][1] = 0.f; acc[k][2] = 0.f; acc[k][3] = 0.f;
    }

    const float* fmb = fm + (size_t)b * CDIM * HW;

    for (int tile = 0; tile < CHUNK / TILE; ++tile) {
        const int ct = c0 + tile * TILE;
        __syncthreads();
        // --- stage fm tile: TILE*HW = 6272 contiguous floats, scatter to padded rows ---
        const float4* src = (const float4*)(fmb + ct * HW);
        for (int i = tid; i < (TILE * HW) / 4; i += 256) {
            float4 v = src[i];
            int e = i * 4;
            int cl = e / HW; int h = e - cl * HW; fm_t[cl * ROWP + h] = v.x;
            e++; cl = e / HW; h = e - cl * HW;    fm_t[cl * ROWP + h] = v.y;
            e++; cl = e / HW; h = e - cl * HW;    fm_t[cl * ROWP + h] = v.z;
            e++; cl = e / HW; h = e - cl * HW;    fm_t[cl * ROWP + h] = v.w;
        }
        // --- stage w tile transposed: w_t[cc][k] ---
        for (int i = tid; i < KDIM * TILE; i += 256) {
            int kk = i >> 7; int cc = i & 127;
            w_t[cc * KDIM + kk] = w16[kk * CDIM + ct + cc];
        }
        __syncthreads();
        // --- compute: 8 cc per thread; per cc: 1 fm b128 + 4 w b128 (uniform) + 64 FMA ---
        #pragma unroll 2
        for (int j = 0; j < 8; ++j) {
            const int cc = cs * 8 + j;
            float4 f = *(const float4*)&fm_t[cc * ROWP + 4 * h4];
            const float4* wq = (const float4*)&w_t[cc * KDIM];
            float wv[16];
            *(float4*)&wv[0]  = wq[0];
            *(float4*)&wv[4]  = wq[1];
            *(float4*)&wv[8]  = wq[2];
            *(float4*)&wv[12] = wq[3];
            #pragma unroll
            for (int k = 0; k < 16; ++k) {
                acc[k][0] += wv[k] * f.x;
                acc[k][1] += wv[k] * f.y;
                acc[k][2] += wv[k] * f.z;
                acc[k][3] += wv[k] * f.w;
            }
        }
    }

    // --- reduce over the 16 c-slices via LDS, 4 k's per round (aliases fm_t) ---
    __syncthreads();
    float* red = fm_t;   // needs 16*272 = 4352 floats <= 6672
    for (int r = 0; r < 4; ++r) {
        #pragma unroll
        for (int kk = 0; kk < 4; ++kk)
            #pragma unroll
            for (int hl = 0; hl < 4; ++hl)
                red[cs * 272 + h4 * 17 + kk * 4 + hl] = acc[r * 4 + kk][hl];
        __syncthreads();
        const int kp = r * 4 + (tid >> 6);
        const int hw = tid & 63;
        if (hw < HW) {
            float s = 0.f;
            const int base = (hw >> 2) * 17 + (tid >> 6) * 4 + (hw & 3);
            #pragma unroll
            for (int c = 0; c < 16; ++c) s += red[c * 272 + base];
            Ppart[(size_t)blockIdx.x * 784 + kp * HW + hw] = s;
        }
        __syncthreads();
    }
}

// ---------------------------------------------------------------------------
// Kernel B: reduce 4 partials, apply BN + 1/49, then
// out[b][k][c] = sum_hw P_bn[k][hw] * fm[b][c][hw]
// grid = BATCH*8, block = 256. Thread t owns c = (blockIdx&7)*256 + t.
// fm slice staged through LDS (coalesced b128 in, conflict-free b32 out).
// ---------------------------------------------------------------------------
__global__ __launch_bounds__(256) void bp_kernel(
    const float* __restrict__ fm, const float* __restrict__ Ppart,
    const float* __restrict__ gamma, const float* __restrict__ beta,
    const float* __restrict__ mean, const float* __restrict__ var,
    float* __restrict__ out)
{
    __shared__ __align__(16) float Pt[HW * KDIM];      // [hw][k], 3136B
    __shared__ __align__(16) float fm_s[256 * HW];     // flat, row stride 49 (odd -> no conflicts)

    const int tid = threadIdx.x;
    const int b   = blockIdx.x >> 3;
    const int c0  = (blockIdx.x & 7) * 256;

    // phase 0: reduce partials + BN + fold 1/49, store transposed [hw][k]
    for (int p = tid; p < 784; p += 256) {
        const float* pp = Ppart + (size_t)(b * 4) * 784 + p;
        float s = pp[0] + pp[784] + pp[1568] + pp[2352];
        int kk = p / HW; int hw = p - kk * HW;
        float inv   = gamma[kk] * rsqrtf(var[kk] + 1e-5f);
        float shift = beta[kk] - mean[kk] * inv;
        Pt[hw * KDIM + kk] = (s * inv + shift) * (1.0f / 49.0f);
    }

    // stage fm slice: 256*49 floats = 12544 float4, fully coalesced + contiguous
    {
        const float4* src = (const float4*)(fm + ((size_t)b * CDIM + c0) * HW);
        float4* dst = (float4*)fm_s;
        #pragma unroll 7
        for (int i = tid; i < (256 * HW) / 4; i += 256) dst[i] = src[i];
    }
    __syncthreads();

    float acc[16];
    #pragma unroll
    for (int i = 0; i < 16; ++i) acc[i] = 0.f;

    const float* row = fm_s + tid * HW;
    #pragma unroll 7
    for (int hw = 0; hw < HW; ++hw) {
        float f = row[hw];
        const float4* pv = (const float4*)&Pt[hw * KDIM];
        float4 p0 = pv[0], p1 = pv[1], p2 = pv[2], p3 = pv[3];
        acc[0]  += p0.x * f; acc[1]  += p0.y * f; acc[2]  += p0.z * f; acc[3]  += p0.w * f;
        acc[4]  += p1.x * f; acc[5]  += p1.y * f; acc[6]  += p1.z * f; acc[7]  += p1.w * f;
        acc[8]  += p2.x * f; acc[9]  += p2.y * f; acc[10] += p2.z * f; acc[11] += p2.w * f;
        acc[12] += p3.x * f; acc[13] += p3.y * f; acc[14] += p3.z * f; acc[15] += p3.w * f;
    }

    float* ob = out + (size_t)b * (KDIM * CDIM) + c0 + tid;
    #pragma unroll
    for (int kk = 0; kk < 16; ++kk) ob[kk * CDIM] = acc[kk];
}

extern "C" void kernel_launch(void* const* d_in, const int* in_sizes, int n_in,
                              void* d_out, int out_size, void* d_ws, size_t ws_size,
                              hipStream_t stream) {
    const float* fm    = (const float*)d_in[0];
    const float* w16   = (const float*)d_in[1];
    const float* gamma = (const float*)d_in[2];
    const float* beta  = (const float*)d_in[3];
    const float* mean  = (const float*)d_in[4];
    const float* var   = (const float*)d_in[5];
    float* out   = (float*)d_out;
    float* Ppart = (float*)d_ws;   // needs BATCH*4*784*4 = 3.2 MB

    pconv_kernel<<<BATCH * 4, 256, 0, stream>>>(fm, w16, Ppart);
    bp_kernel<<<BATCH * 8, 256, 0, stream>>>(fm, Ppart, gamma, beta, mean, var, out);
}